// Round 9
// baseline (601.786 us; speedup 1.0000x reference)
//
#include <hip/hip_runtime.h>

typedef __bf16 bf16_t;
typedef __bf16 bf16x8 __attribute__((ext_vector_type(8)));
typedef __bf16 bf16x4 __attribute__((ext_vector_type(4)));
typedef float  f32x4  __attribute__((ext_vector_type(4)));

#define SEQ   2048
#define DMODEL 1024
#define DFF   4096
#define NHEAD 16
#define HDIM  64
#define MTOK  8192   // 4 * 2048

// Q is pre-scaled by (1/sqrt(64)) * log2(e) so attention softmax runs in exp2 domain.
#define QSCALE 0.18033688f
#define THR_LOG2 11.5f

// ---------------- workspace layout (bytes) ----------------
#define MB (size_t)(1024*1024)
static const size_t XB_OFF   = 0;          // bf16 [8192][1024]  (aliased by FFN1 later)
static const size_t Q_OFF    = 16*MB;      // bf16 [B,H,S,64]
static const size_t K_OFF    = 32*MB;      // bf16 [B,H,S,64]
static const size_t VT_OFF   = 48*MB;      // bf16 [B,H,64,S]
static const size_t FFN1_OFF = 0;          // bf16 [8192][4096] aliases XB..VT (all dead then)
static const size_t CTX_OFF  = 64*MB;      // bf16 [8192][1024]
static const size_t OUT1_OFF = 80*MB;      // f32  [8192][1024]; bias-concat scratch earlier
static const size_t LN1_OFF  = 112*MB;     // bf16 [8192][1024]
static const size_t WQKV_OFF = 128*MB;     // bf16 [3072][1024] (Q,K,V rows concat)
static const size_t WO_OFF   = 134*MB;
static const size_t W1_OFF   = 136*MB;     // bf16 [4096][1024]
static const size_t W2_OFF   = 144*MB;     // bf16 [1024][4096]  (ends at 152MB)

// ---------------- helpers ----------------
__device__ inline void gload16(const void* g, void* l) {
    __builtin_amdgcn_global_load_lds((__attribute__((address_space(1))) void*)g,
                                     (__attribute__((address_space(3))) void*)l, 16, 0, 0);
}

__global__ __launch_bounds__(256) void cast_bf16_k(const float* __restrict__ s,
                                                   bf16_t* __restrict__ d, int n8) {
    int i = blockIdx.x * 256 + threadIdx.x;
    if (i >= n8) return;
    float4 v0 = ((const float4*)s)[2*i];
    float4 v1 = ((const float4*)s)[2*i+1];
    bf16x8 o;
    o[0]=(bf16_t)v0.x; o[1]=(bf16_t)v0.y; o[2]=(bf16_t)v0.z; o[3]=(bf16_t)v0.w;
    o[4]=(bf16_t)v1.x; o[5]=(bf16_t)v1.y; o[6]=(bf16_t)v1.z; o[7]=(bf16_t)v1.w;
    *(bf16x8*)(d + (size_t)i*8) = o;
}

__global__ __launch_bounds__(256) void concat_bias_k(const float* __restrict__ a,
                                                     const float* __restrict__ b,
                                                     const float* __restrict__ c,
                                                     float* __restrict__ o) {
    int i = blockIdx.x * 256 + threadIdx.x;   // grid 12*256 = 3072
    o[i] = (i < 1024) ? a[i] : ((i < 2048) ? b[i - 1024] : c[i - 2048]);
}

// ---------------- 128x128 GEMM (m97-class): used for Wo (EPI2) and FFN2 (EPI4) ----------------
template<int EPI>
__global__ __launch_bounds__(256, 2) void gemm_bt(
    const bf16_t* __restrict__ A, const bf16_t* __restrict__ Bm,
    const float* __restrict__ bias, void* __restrict__ out,
    const float* __restrict__ aux, int M, int N, int K, float scale)
{
    __shared__ bf16_t As[128*64];
    __shared__ bf16_t Bs[128*64];
    const int tid = threadIdx.x;
    const int l   = tid & 63;
    const int wid = tid >> 6;
    const int wm  = wid >> 1, wn = wid & 1;
    const int c16 = l & 15,   g  = l >> 4;
    int lin = blockIdx.y * gridDim.x + blockIdx.x;
    int nwg = gridDim.x * gridDim.y;
    int swz = (lin & 7) * (nwg >> 3) + (lin >> 3);
    const long brow = (long)(swz / gridDim.x) * 128;
    const long bcol = (long)(swz % gridDim.x) * 128;

    f32x4 acc[4][4] = {};

    const int nkt = K >> 6;
    for (int kt = 0; kt < nkt; ++kt) {
        __syncthreads();
        const bf16_t* Ag = A  + brow * K + kt*64;
        const bf16_t* Bg = Bm + bcol * K + kt*64;
#pragma unroll
        for (int c = 0; c < 4; ++c) {
            int e   = (c*256 + tid) * 8;
            int row = e >> 6;
            int col = e & 63;
            gload16(Ag + (long)row*K + col, &As[e]);
            gload16(Bg + (long)row*K + col, &Bs[e]);
        }
        __syncthreads();
#pragma unroll
        for (int kk = 0; kk < 2; ++kk) {
            bf16x8 af[4], bfr[4];
#pragma unroll
            for (int mi = 0; mi < 4; ++mi)
                af[mi] = *(const bf16x8*)&As[(wm*64 + mi*16 + c16)*64 + kk*32 + 8*g];
#pragma unroll
            for (int ni = 0; ni < 4; ++ni)
                bfr[ni] = *(const bf16x8*)&Bs[(wn*64 + ni*16 + c16)*64 + kk*32 + 8*g];
#pragma unroll
            for (int mi = 0; mi < 4; ++mi)
#pragma unroll
                for (int ni = 0; ni < 4; ++ni)
                    acc[mi][ni] = __builtin_amdgcn_mfma_f32_16x16x32_bf16(
                        af[mi], bfr[ni], acc[mi][ni], 0, 0, 0);
        }
    }

#pragma unroll
    for (int ni = 0; ni < 4; ++ni) {
        const long c = bcol + wn*64 + ni*16 + c16;
        const float bv = bias[c];
#pragma unroll
        for (int mi = 0; mi < 4; ++mi) {
#pragma unroll
            for (int i = 0; i < 4; ++i) {
                const long r = brow + wm*64 + mi*16 + g*4 + i;
                float v = (acc[mi][ni][i] + bv) * scale;
                if constexpr (EPI == 2) {
                    ((float*)out)[r*N + c] = v;
                } else {
                    ((float*)out)[r*N + c] = v + aux[r*N + c];
                }
            }
        }
    }
}

// ---------------- 256x256 8-phase GEMM (m201 template, T2+T3+T4+T5) ----------------
template<int EPI>
__global__ __launch_bounds__(512, 2) void gemm256(
    const bf16_t* __restrict__ A, const bf16_t* __restrict__ Bm,
    const float* __restrict__ bias, void* __restrict__ out,
    void* __restrict__ out_k, void* __restrict__ out_v,
    int M, int N, int K)
{
    __shared__ alignas(16) char lds[131072];
    const int tid = threadIdx.x;
    const int l   = tid & 63;
    const int wid = tid >> 6;            // 0..7
    const int wm  = wid >> 2, wn = wid & 3;
    const int c16 = l & 15,   g  = l >> 4;
    const int xsw = (c16 & 7) << 4;

    int lin = blockIdx.y * gridDim.x + blockIdx.x;
    int nwg = gridDim.x * gridDim.y;
    int swz = (lin & 7) * (nwg >> 3) + (lin >> 3);
    const long brow = (long)(swz / gridDim.x) * 256;
    const long bcol = (long)(swz % gridDim.x) * 256;

    const int rowloc = tid >> 3;
    const int srcblk = (tid & 7) ^ ((tid >> 3) & 7);
    const bf16_t* Asrc = A  + (brow + rowloc) * (long)K + srcblk * 8;
    const bf16_t* Bsrc = Bm + (bcol + rowloc) * (long)K + srcblk * 8;

    f32x4 acc[8][4] = {};
    const int NKT = K >> 6;

    auto stA = [&](int cur, int t, int j) {
        gload16(Asrc + (long)j*64*K + (long)t*64, lds + cur*65536 + j*8192 + tid*16);
    };
    auto stB = [&](int cur, int t, int j) {
        gload16(Bsrc + (long)j*64*K + (long)t*64, lds + cur*65536 + 32768 + j*8192 + tid*16);
    };

#pragma unroll
    for (int j = 0; j < 4; ++j) stA(0, 0, j);
#pragma unroll
    for (int j = 0; j < 4; ++j) stB(0, 0, j);
#pragma unroll
    for (int j = 0; j < 4; ++j) stA(1, 1, j);
#pragma unroll
    for (int j = 0; j < 4; ++j) stB(1, 1, j);
    asm volatile("s_waitcnt vmcnt(8)" ::: "memory");
    __builtin_amdgcn_sched_barrier(0);
    __builtin_amdgcn_s_barrier();

    int cur = 0;
    for (int t = 0; t < NKT; ++t, cur ^= 1) {
        const char* aL = lds + cur*65536;
        const char* bL = aL + 32768;
        const bool stg = (t + 2 < NKT);
        bf16x8 a0[4][2], a1[4][2], b0[2][2], b1[2][2];

#pragma unroll
        for (int mi = 0; mi < 4; ++mi)
#pragma unroll
            for (int kk = 0; kk < 2; ++kk)
                a0[mi][kk] = *(const bf16x8*)(aL + (wm*128 + mi*16 + c16)*128 + ((kk*64 + 16*g) ^ xsw));
#pragma unroll
        for (int ni = 0; ni < 2; ++ni)
#pragma unroll
            for (int kk = 0; kk < 2; ++kk)
                b0[ni][kk] = *(const bf16x8*)(bL + (wn*64 + ni*16 + c16)*128 + ((kk*64 + 16*g) ^ xsw));
        __builtin_amdgcn_s_barrier();
        asm volatile("s_waitcnt lgkmcnt(0)" ::: "memory");
        __builtin_amdgcn_sched_barrier(0);
        __builtin_amdgcn_s_setprio(1);
#pragma unroll
        for (int mi = 0; mi < 4; ++mi)
#pragma unroll
            for (int ni = 0; ni < 2; ++ni)
#pragma unroll
                for (int kk = 0; kk < 2; ++kk)
                    acc[mi][ni] = __builtin_amdgcn_mfma_f32_16x16x32_bf16(a0[mi][kk], b0[ni][kk], acc[mi][ni], 0, 0, 0);
        __builtin_amdgcn_s_setprio(0);
        __builtin_amdgcn_s_barrier();

#pragma unroll
        for (int ni = 0; ni < 2; ++ni)
#pragma unroll
            for (int kk = 0; kk < 2; ++kk)
                b1[ni][kk] = *(const bf16x8*)(bL + (wn*64 + (ni+2)*16 + c16)*128 + ((kk*64 + 16*g) ^ xsw));
        if (stg) { stA(cur, t+2, 0); stA(cur, t+2, 2); }
        __builtin_amdgcn_s_barrier();
        asm volatile("s_waitcnt lgkmcnt(0)" ::: "memory");
        __builtin_amdgcn_sched_barrier(0);
        __builtin_amdgcn_s_setprio(1);
#pragma unroll
        for (int mi = 0; mi < 4; ++mi)
#pragma unroll
            for (int ni = 0; ni < 2; ++ni)
#pragma unroll
                for (int kk = 0; kk < 2; ++kk)
                    acc[mi][ni+2] = __builtin_amdgcn_mfma_f32_16x16x32_bf16(a0[mi][kk], b1[ni][kk], acc[mi][ni+2], 0, 0, 0);
        __builtin_amdgcn_s_setprio(0);
        __builtin_amdgcn_s_barrier();

#pragma unroll
        for (int mi = 0; mi < 4; ++mi)
#pragma unroll
            for (int kk = 0; kk < 2; ++kk)
                a1[mi][kk] = *(const bf16x8*)(aL + (wm*128 + (mi+4)*16 + c16)*128 + ((kk*64 + 16*g) ^ xsw));
        if (stg) { stB(cur, t+2, 0); stB(cur, t+2, 1); }
        __builtin_amdgcn_s_barrier();
        asm volatile("s_waitcnt lgkmcnt(0)" ::: "memory");
        __builtin_amdgcn_sched_barrier(0);
        __builtin_amdgcn_s_setprio(1);
#pragma unroll
        for (int mi = 0; mi < 4; ++mi)
#pragma unroll
            for (int ni = 0; ni < 2; ++ni)
#pragma unroll
                for (int kk = 0; kk < 2; ++kk)
                    acc[mi+4][ni] = __builtin_amdgcn_mfma_f32_16x16x32_bf16(a1[mi][kk], b0[ni][kk], acc[mi+4][ni], 0, 0, 0);
        __builtin_amdgcn_s_setprio(0);
        __builtin_amdgcn_s_barrier();

        if (stg) { stA(cur, t+2, 1); stA(cur, t+2, 3); stB(cur, t+2, 2); stB(cur, t+2, 3); }
        __builtin_amdgcn_s_barrier();
        __builtin_amdgcn_s_setprio(1);
#pragma unroll
        for (int mi = 0; mi < 4; ++mi)
#pragma unroll
            for (int ni = 0; ni < 2; ++ni)
#pragma unroll
                for (int kk = 0; kk < 2; ++kk)
                    acc[mi+4][ni+2] = __builtin_amdgcn_mfma_f32_16x16x32_bf16(a1[mi][kk], b1[ni][kk], acc[mi+4][ni+2], 0, 0, 0);
        __builtin_amdgcn_s_setprio(0);
        if (stg)                asm volatile("s_waitcnt vmcnt(8)" ::: "memory");
        else if (t < NKT - 1)   asm volatile("s_waitcnt vmcnt(0)" ::: "memory");
        __builtin_amdgcn_sched_barrier(0);
        __builtin_amdgcn_s_barrier();
    }

#pragma unroll
    for (int ni = 0; ni < 4; ++ni) {
        const long c = bcol + wn*64 + ni*16 + c16;
        const float bv = bias[c];
#pragma unroll
        for (int mi = 0; mi < 8; ++mi) {
#pragma unroll
            for (int i = 0; i < 4; ++i) {
                const long r = brow + wm*128 + mi*16 + g*4 + i;
                float v = acc[mi][ni][i] + bv;
                if constexpr (EPI == 3) {
                    ((bf16_t*)out)[r*N + c] = (bf16_t)fmaxf(v, 0.f);
                } else {   // EPI 5
                    const int mat = (int)(c >> 10);
                    const int hc  = (int)(c & 1023);
                    const long bb = r >> 11, sidx = r & (SEQ-1);
                    const long hb = bb*NHEAD + (hc >> 6);
                    if (mat == 0)
                        ((bf16_t*)out)[(hb*SEQ + sidx)*HDIM + (hc & 63)] = (bf16_t)(v * QSCALE);
                    else if (mat == 1)
                        ((bf16_t*)out_k)[(hb*SEQ + sidx)*HDIM + (hc & 63)] = (bf16_t)v;
                    else
                        ((bf16_t*)out_v)[(hb*HDIM + (hc & 63))*SEQ + sidx] = (bf16_t)v;
                }
            }
        }
    }
}

// ---------------- flash attention: swapped-QK, exp2 domain, shuffle-free steady softmax ----------------
// R6 pipeline structure (verified 249us, VGPR 116). This round: softmax steady state has
// ZERO cross-lane shuffles — local 16-key max + __any vote (defer-max); per-lane partial ls
// merged once at the end; exp2f native (log2e folded into Q scale).
__device__ __forceinline__ void kload(bf16x8 (&dst)[4][2], const bf16_t* kb0,
                                      int ktt, int c16, int g) {
    const bf16_t* kbase = kb0 + (size_t)ktt*64*HDIM;
#pragma unroll
    for (int jk = 0; jk < 4; ++jk)
#pragma unroll
        for (int ks = 0; ks < 2; ++ks)
            dst[jk][ks] = *(const bf16x8*)(kbase + (size_t)(16*jk + c16)*HDIM + ks*32 + 8*g);
}

__device__ __forceinline__ void vload(bf16x8 (&vr)[4][2], const bf16_t* vt0,
                                      int ktt, int c16, int g) {
#pragma unroll
    for (int nf = 0; nf < 4; ++nf)
#pragma unroll
        for (int ks = 0; ks < 2; ++ks)
            vr[nf][ks] = *(const bf16x8*)(vt0 + (size_t)(16*nf + c16)*SEQ + ktt*64 + ks*32 + 8*g);
}

__device__ __forceinline__ void qk_step(f32x4 (&s)[2][4], const bf16x8 (&kr)[4][2],
                                        const bf16x8 (&aq)[2][2]) {
    const f32x4 z = {0.f, 0.f, 0.f, 0.f};
    __builtin_amdgcn_s_setprio(1);
#pragma unroll
    for (int qf = 0; qf < 2; ++qf)
#pragma unroll
        for (int jk = 0; jk < 4; ++jk) {
            s[qf][jk] = __builtin_amdgcn_mfma_f32_16x16x32_bf16(kr[jk][0], aq[qf][0], z, 0, 0, 0);
            s[qf][jk] = __builtin_amdgcn_mfma_f32_16x16x32_bf16(kr[jk][1], aq[qf][1], s[qf][jk], 0, 0, 0);
        }
    __builtin_amdgcn_s_setprio(0);
}

// s in log2 domain. m per-lane (uniform across the 4 g-lanes of each q). ls = per-lane partial.
__device__ __forceinline__ void sm_step(f32x4 (&s)[2][4], f32x4 (&acc)[2][4],
                                        float (&m)[2], float (&ls)[2], int g) {
#pragma unroll
    for (int qf = 0; qf < 2; ++qf) {
        // local 16-key max (tree)
        f32x4 t01, t23, t03;
#pragma unroll
        for (int i = 0; i < 4; ++i) {
            t01[i] = fmaxf(s[qf][0][i], s[qf][1][i]);
            t23[i] = fmaxf(s[qf][2][i], s[qf][3][i]);
        }
#pragma unroll
        for (int i = 0; i < 4; ++i) t03[i] = fmaxf(t01[i], t23[i]);
        float lmax = fmaxf(fmaxf(t03[0], t03[1]), fmaxf(t03[2], t03[3]));
        // defer-max: steady state has NO cross-lane shuffles; vote covers all 64 lanes
        if (__any(lmax > m[qf] + THR_LOG2)) {
            float pm = lmax;
            pm = fmaxf(pm, __shfl_xor(pm, 16, 64));
            pm = fmaxf(pm, __shfl_xor(pm, 32, 64));
            float mn   = fmaxf(m[qf], pm);
            float corr = __builtin_exp2f(m[qf] - mn);
            ls[qf] *= corr;
            m[qf]   = mn;
            float c0 = __shfl(corr, 4*g + 0, 64);
            float c1 = __shfl(corr, 4*g + 1, 64);
            float c2 = __shfl(corr, 4*g + 2, 64);
            float c3 = __shfl(corr, 4*g + 3, 64);
#pragma unroll
            for (int nf = 0; nf < 4; ++nf) {
                acc[qf][nf][0] *= c0; acc[qf][nf][1] *= c1;
                acc[qf][nf][2] *= c2; acc[qf][nf][3] *= c3;
            }
        }
#pragma unroll
        for (int jk = 0; jk < 4; ++jk)
#pragma unroll
            for (int i = 0; i < 4; ++i)
                s[qf][jk][i] = __builtin_exp2f(s[qf][jk][i] - m[qf]);
        // per-lane partial sum (tree); cross-lane merge deferred to epilogue
        f32x4 r01, r23, r;
#pragma unroll
        for (int i = 0; i < 4; ++i) {
            r01[i] = s[qf][0][i] + s[qf][1][i];
            r23[i] = s[qf][2][i] + s[qf][3][i];
        }
#pragma unroll
        for (int i = 0; i < 4; ++i) r[i] = r01[i] + r23[i];
        ls[qf] += (r[0] + r[1]) + (r[2] + r[3]);
    }
}

__device__ __forceinline__ void pwrite_step(const f32x4 (&s)[2][4], char* buf, int c16, int g) {
#pragma unroll
    for (int qf = 0; qf < 2; ++qf)
#pragma unroll
        for (int jk = 0; jk < 4; ++jk) {
            bf16x4 pk;
            pk[0]=(bf16_t)s[qf][jk][0]; pk[1]=(bf16_t)s[qf][jk][1];
            pk[2]=(bf16_t)s[qf][jk][2]; pk[3]=(bf16_t)s[qf][jk][3];
            *(bf16x4*)(buf + (qf*16 + c16)*128 + ((32*jk + 8*g) ^ ((c16 & 7) << 4))) = pk;
        }
}

__device__ __forceinline__ void pv_step(f32x4 (&acc)[2][4], const bf16x8 (&vr)[4][2],
                                        const char* buf, int c16, int g) {
    __builtin_amdgcn_s_setprio(1);
#pragma unroll
    for (int qf = 0; qf < 2; ++qf)
#pragma unroll
        for (int ks = 0; ks < 2; ++ks) {
            bf16x8 pa = *(const bf16x8*)(buf + (qf*16 + c16)*128 + ((ks*64 + 16*g) ^ ((c16 & 7) << 4)));
#pragma unroll
            for (int nf = 0; nf < 4; ++nf)
                acc[qf][nf] = __builtin_amdgcn_mfma_f32_16x16x32_bf16(pa, vr[nf][ks], acc[qf][nf], 0, 0, 0);
        }
    __builtin_amdgcn_s_setprio(0);
}

__global__ __launch_bounds__(256, 2) void attn_k(
    const bf16_t* __restrict__ qb, const bf16_t* __restrict__ kb,
    const bf16_t* __restrict__ vt, bf16_t* __restrict__ ctx)
{
    const int id  = blockIdx.x;
    const int idx = id >> 3;
    const int bh  = (id & 7) + 8 * (idx & 7);
    const int qt  = idx >> 3;
    const int w   = threadIdx.x >> 6;
    const int l   = threadIdx.x & 63;
    const int c16 = l & 15, g = l >> 4;
    const int q0  = qt*128 + w*32;

    __shared__ char Ps[4*8192];
    char* myP = &Ps[w*8192];

    bf16x8 aq[2][2];
#pragma unroll
    for (int qf = 0; qf < 2; ++qf) {
        const bf16_t* qrow = qb + ((size_t)bh*SEQ + q0 + qf*16 + c16)*HDIM;
        aq[qf][0] = *(const bf16x8*)(qrow + 8*g);
        aq[qf][1] = *(const bf16x8*)(qrow + 32 + 8*g);
    }

    const bf16_t* kb0 = kb + (size_t)bh*SEQ*HDIM;
    const bf16_t* vt0 = vt + (size_t)bh*HDIM*SEQ;

    f32x4 acc[2][4] = {};
    float m[2]  = {-1e30f, -1e30f};
    float ls[2] = {0.f, 0.f};

    bf16x8 kA[4][2], kB[4][2], vA[4][2], vB[4][2];
    f32x4 s[2][4];

    kload(kA, kb0, 0, c16, g);
    vload(vA, vt0, 0, c16, g);
    kload(kB, kb0, 1, c16, g);
    qk_step(s, kA, aq);
    sm_step(s, acc, m, ls, g);
    pwrite_step(s, myP, c16, g);

    const int NT = SEQ/64;   // 32
    for (int t = 0; t < NT - 2; t += 2) {
        qk_step(s, kB, aq);
        asm volatile("s_waitcnt lgkmcnt(0)" ::: "memory");
        __builtin_amdgcn_sched_barrier(0);
        kload(kA, kb0, t + 2, c16, g);
        vload(vB, vt0, t + 1, c16, g);
        __builtin_amdgcn_sched_barrier(0);
        pv_step(acc, vA, myP, c16, g);
        sm_step(s, acc, m, ls, g);
        pwrite_step(s, myP + 4096, c16, g);
        qk_step(s, kA, aq);
        asm volatile("s_waitcnt lgkmcnt(0)" ::: "memory");
        __builtin_amdgcn_sched_barrier(0);
        kload(kB, kb0, t + 3, c16, g);
        vload(vA, vt0, t + 2, c16, g);
        __builtin_amdgcn_sched_barrier(0);
        pv_step(acc, vB, myP + 4096, c16, g);
        sm_step(s, acc, m, ls, g);
        pwrite_step(s, myP, c16, g);
    }
    qk_step(s, kB, aq);
    asm volatile("s_waitcnt lgkmcnt(0)" ::: "memory");
    __builtin_amdgcn_sched_barrier(0);
    vload(vB, vt0, NT - 1, c16, g);
    __builtin_amdgcn_sched_barrier(0);
    pv_step(acc, vA, myP, c16, g);
    sm_step(s, acc, m, ls, g);
    pwrite_step(s, myP + 4096, c16, g);
    asm volatile("s_waitcnt lgkmcnt(0)" ::: "memory");
    __builtin_amdgcn_sched_barrier(0);
    pv_step(acc, vB, myP + 4096, c16, g);

    const int b = bh >> 4, h = bh & 15;
#pragma unroll
    for (int qf = 0; qf < 2; ++qf) {
        // merge per-lane partial ls across the 4 g-groups (once per kernel)
        float lst = ls[qf];
        lst += __shfl_xor(lst, 16, 64);
        lst += __shfl_xor(lst, 32, 64);
        float i0 = 1.0f / __shfl(lst, 4*g + 0, 64);
        float i1 = 1.0f / __shfl(lst, 4*g + 1, 64);
        float i2 = 1.0f / __shfl(lst, 4*g + 2, 64);
        float i3 = 1.0f / __shfl(lst, 4*g + 3, 64);
#pragma unroll
        for (int nf = 0; nf < 4; ++nf) {
            long col = (size_t)h*HDIM + nf*16 + c16;
            long rb  = (size_t)b*SEQ + q0 + qf*16 + 4*g;
            ctx[(rb + 0)*DMODEL + col] = (bf16_t)(acc[qf][nf][0] * i0);
            ctx[(rb + 1)*DMODEL + col] = (bf16_t)(acc[qf][nf][1] * i1);
            ctx[(rb + 2)*DMODEL + col] = (bf16_t)(acc[qf][nf][2] * i2);
            ctx[(rb + 3)*DMODEL + col] = (bf16_t)(acc[qf][nf][3] * i3);
        }
    }
}

// ---------------- layer norm: one block per row of 1024 ----------------
__global__ __launch_bounds__(256) void ln_k(
    const float* __restrict__ a, const float* __restrict__ b,
    const float* __restrict__ g, const float* __restrict__ be,
    float* __restrict__ of, bf16_t* __restrict__ ob)
{
    const long row = blockIdx.x;
    const int tid = threadIdx.x;
    float4 v = ((const float4*)(a + row*DMODEL))[tid];
    if (b) {
        float4 u = ((const float4*)(b + row*DMODEL))[tid];
        v.x += u.x; v.y += u.y; v.z += u.z; v.w += u.w;
    }
    float s = v.x + v.y + v.z + v.w;
    float q = v.x*v.x + v.y*v.y + v.z*v.z + v.w*v.w;
#pragma unroll
    for (int msk = 1; msk < 64; msk <<= 1) {
        s += __shfl_xor(s, msk, 64);
        q += __shfl_xor(q, msk, 64);
    }
    __shared__ float sb[4], qb2[4];
    int w = tid >> 6, lid = tid & 63;
    if (lid == 0) { sb[w] = s; qb2[w] = q; }
    __syncthreads();
    s = sb[0] + sb[1] + sb[2] + sb[3];
    q = qb2[0] + qb2[1] + qb2[2] + qb2[3];
    float mean = s * (1.f/1024.f);
    float var  = q * (1.f/1024.f) - mean*mean;
    float rs   = rsqrtf(var + 1e-5f);
    float4 gv = ((const float4*)g)[tid];
    float4 bv = ((const float4*)be)[tid];
    float o0 = (v.x-mean)*rs*gv.x + bv.x;
    float o1 = (v.y-mean)*rs*gv.y + bv.y;
    float o2 = (v.z-mean)*rs*gv.z + bv.z;
    float o3 = (v.w-mean)*rs*gv.w + bv.w;
    if (ob) {
        bf16x4 o; o[0]=(bf16_t)o0; o[1]=(bf16_t)o1; o[2]=(bf16_t)o2; o[3]=(bf16_t)o3;
        *(bf16x4*)(ob + row*DMODEL + tid*4) = o;
    } else {
        float4 o = make_float4(o0, o1, o2, o3);
        ((float4*)(of + row*DMODEL))[tid] = o;
    }
}

// ---------------- host ----------------
extern "C" void kernel_launch(void* const* d_in, const int* in_sizes, int n_in,
                              void* d_out, int out_size, void* d_ws, size_t ws_size,
                              hipStream_t stream)
{
    const float* x   = (const float*)d_in[0];
    const float* Wq  = (const float*)d_in[1];
    const float* bq  = (const float*)d_in[2];
    const float* Wk  = (const float*)d_in[3];
    const float* bk  = (const float*)d_in[4];
    const float* Wv  = (const float*)d_in[5];
    const float* bvv = (const float*)d_in[6];
    const float* Wo  = (const float*)d_in[7];
    const float* bo  = (const float*)d_in[8];
    const float* W1  = (const float*)d_in[9];
    const float* b1  = (const float*)d_in[10];
    const float* W2  = (const float*)d_in[11];
    const float* b2  = (const float*)d_in[12];
    const float* g1  = (const float*)d_in[13];
    const float* be1 = (const float*)d_in[14];
    const float* g2  = (const float*)d_in[15];
    const float* be2 = (const float*)d_in[16];

    char* ws = (char*)d_ws;
    bf16_t* xb   = (bf16_t*)(ws + XB_OFF);
    bf16_t* qbuf = (bf16_t*)(ws + Q_OFF);
    bf16_t* kbuf = (bf16_t*)(ws + K_OFF);
    bf16_t* vtb  = (bf16_t*)(ws + VT_OFF);
    bf16_t* ffn1 = (bf16_t*)(ws + FFN1_OFF);
    bf16_t* ctxb = (bf16_t*)(ws + CTX_OFF);
    float*  out1 = (float*)(ws + OUT1_OFF);
    bf16_t* ln1b = (bf16_t*)(ws + LN1_OFF);
    bf16_t* wqkv = (bf16_t*)(ws + WQKV_OFF);
    bf16_t* wob  = (bf16_t*)(ws + WO_OFF);
    bf16_t* w1b  = (bf16_t*)(ws + W1_OFF);
    bf16_t* w2b  = (bf16_t*)(ws + W2_OFF);
    float*  biasc= (float*)(ws + OUT1_OFF);   // 3072 floats, dead before Wo writes out1
    float*  dout = (float*)d_out;

    auto cast = [&](const float* s, bf16_t* d, long n) {
        int n8 = (int)(n / 8);
        cast_bf16_k<<<(n8 + 255)/256, 256, 0, stream>>>(s, d, n8);
    };
    cast(x,  xb,  (long)MTOK*DMODEL);
    cast(Wq, wqkv,                        (long)DMODEL*DMODEL);
    cast(Wk, wqkv + (long)DMODEL*DMODEL,  (long)DMODEL*DMODEL);
    cast(Wv, wqkv + 2L*DMODEL*DMODEL,     (long)DMODEL*DMODEL);
    cast(Wo, wob, (long)DMODEL*DMODEL);
    cast(W1, w1b, (long)DFF*DMODEL);
    cast(W2, w2b, (long)DMODEL*DFF);
    concat_bias_k<<<12, 256, 0, stream>>>(bq, bk, bvv, biasc);

    // fused QKV projection: 256^2 8-phase (Q scaled by QSCALE = 0.125*log2e in epilogue)
    gemm256<5><<<dim3(3*DMODEL/256, MTOK/256), dim3(512), 0, stream>>>(
        xb, wqkv, biasc, qbuf, kbuf, vtb, MTOK, 3*DMODEL, DMODEL);
    // attention
    attn_k<<<dim3((SEQ/128) * 4*NHEAD), dim3(256), 0, stream>>>(qbuf, kbuf, vtb, ctxb);
    // Wo projection -> out1 (fp32), 128^2
    gemm_bt<2><<<dim3(DMODEL/128, MTOK/128), dim3(256), 0, stream>>>(
        ctxb, wob, bo, out1, nullptr, MTOK, DMODEL, DMODEL, 1.f);
    // LN1
    ln_k<<<MTOK, dim3(256), 0, stream>>>(x, out1, g1, be1, nullptr, ln1b);
    // FFN1: relu(ln1 @ W1^T + b1) -> bf16, 256^2 8-phase
    gemm256<3><<<dim3(DFF/256, MTOK/256), dim3(512), 0, stream>>>(
        ln1b, w1b, b1, ffn1, nullptr, nullptr, MTOK, DFF, DMODEL);
    // FFN2: s2 = out1 + (ffn1 @ W2^T + b2) -> fp32 in place, 128^2
    gemm_bt<4><<<dim3(DMODEL/128, MTOK/128), dim3(256), 0, stream>>>(
        ffn1, w2b, b2, out1, out1, MTOK, DMODEL, DFF, 1.f);
    // LN2 -> d_out
    ln_k<<<MTOK, dim3(256), 0, stream>>>(out1, nullptr, g2, be2, dout, nullptr);
}

// Round 10
// 576.031 us; speedup vs baseline: 1.0447x; 1.0447x over previous
//
#include <hip/hip_runtime.h>

typedef __bf16 bf16_t;
typedef __bf16 bf16x8 __attribute__((ext_vector_type(8)));
typedef __bf16 bf16x4 __attribute__((ext_vector_type(4)));
typedef float  f32x4  __attribute__((ext_vector_type(4)));

#define SEQ   2048
#define DMODEL 1024
#define DFF   4096
#define NHEAD 16
#define HDIM  64
#define MTOK  8192   // 4 * 2048

// Q is pre-scaled by (1/sqrt(64)) * log2(e) so attention softmax runs in exp2 domain.
#define QSCALE 0.18033688f
#define THR_LOG2 11.5f

// ---------------- workspace layout (bytes) ----------------
#define MB (size_t)(1024*1024)
static const size_t XB_OFF   = 0;          // bf16 [8192][1024]  (aliased by FFN1 later)
static const size_t Q_OFF    = 16*MB;      // bf16 [B,H,S,64]
static const size_t K_OFF    = 32*MB;      // bf16 [B,H,S,64]
static const size_t VT_OFF   = 48*MB;      // bf16 [B,H,64,S]
static const size_t FFN1_OFF = 0;          // bf16 [8192][4096] aliases XB..VT (all dead then)
static const size_t CTX_OFF  = 64*MB;      // bf16 [8192][1024]
static const size_t OUT1_OFF = 80*MB;      // f32  [8192][1024]; bias-concat scratch earlier
static const size_t LN1_OFF  = 112*MB;     // bf16 [8192][1024]
static const size_t WQKV_OFF = 128*MB;     // bf16 [3072][1024] (Q,K,V rows concat)
static const size_t WO_OFF   = 134*MB;
static const size_t W1_OFF   = 136*MB;     // bf16 [4096][1024]
static const size_t W2_OFF   = 144*MB;     // bf16 [1024][4096]  (ends at 152MB)

// ---------------- helpers ----------------
__device__ inline void gload16(const void* g, void* l) {
    __builtin_amdgcn_global_load_lds((__attribute__((address_space(1))) void*)g,
                                     (__attribute__((address_space(3))) void*)l, 16, 0, 0);
}

__global__ __launch_bounds__(256) void cast_bf16_k(const float* __restrict__ s,
                                                   bf16_t* __restrict__ d, int n8) {
    int i = blockIdx.x * 256 + threadIdx.x;
    if (i >= n8) return;
    float4 v0 = ((const float4*)s)[2*i];
    float4 v1 = ((const float4*)s)[2*i+1];
    bf16x8 o;
    o[0]=(bf16_t)v0.x; o[1]=(bf16_t)v0.y; o[2]=(bf16_t)v0.z; o[3]=(bf16_t)v0.w;
    o[4]=(bf16_t)v1.x; o[5]=(bf16_t)v1.y; o[6]=(bf16_t)v1.z; o[7]=(bf16_t)v1.w;
    *(bf16x8*)(d + (size_t)i*8) = o;
}

__global__ __launch_bounds__(256) void concat_bias_k(const float* __restrict__ a,
                                                     const float* __restrict__ b,
                                                     const float* __restrict__ c,
                                                     float* __restrict__ o) {
    int i = blockIdx.x * 256 + threadIdx.x;   // grid 12*256 = 3072
    o[i] = (i < 1024) ? a[i] : ((i < 2048) ? b[i - 1024] : c[i - 2048]);
}

// ---------------- 128x128 GEMM (m97-class): used for Wo (EPI2) and FFN2 (EPI4) ----------------
template<int EPI>
__global__ __launch_bounds__(256, 2) void gemm_bt(
    const bf16_t* __restrict__ A, const bf16_t* __restrict__ Bm,
    const float* __restrict__ bias, void* __restrict__ out,
    const float* __restrict__ aux, int M, int N, int K, float scale)
{
    __shared__ bf16_t As[128*64];
    __shared__ bf16_t Bs[128*64];
    const int tid = threadIdx.x;
    const int l   = tid & 63;
    const int wid = tid >> 6;
    const int wm  = wid >> 1, wn = wid & 1;
    const int c16 = l & 15,   g  = l >> 4;
    int lin = blockIdx.y * gridDim.x + blockIdx.x;
    int nwg = gridDim.x * gridDim.y;
    int swz = (lin & 7) * (nwg >> 3) + (lin >> 3);
    const long brow = (long)(swz / gridDim.x) * 128;
    const long bcol = (long)(swz % gridDim.x) * 128;

    f32x4 acc[4][4] = {};

    const int nkt = K >> 6;
    for (int kt = 0; kt < nkt; ++kt) {
        __syncthreads();
        const bf16_t* Ag = A  + brow * K + kt*64;
        const bf16_t* Bg = Bm + bcol * K + kt*64;
#pragma unroll
        for (int c = 0; c < 4; ++c) {
            int e   = (c*256 + tid) * 8;
            int row = e >> 6;
            int col = e & 63;
            gload16(Ag + (long)row*K + col, &As[e]);
            gload16(Bg + (long)row*K + col, &Bs[e]);
        }
        __syncthreads();
#pragma unroll
        for (int kk = 0; kk < 2; ++kk) {
            bf16x8 af[4], bfr[4];
#pragma unroll
            for (int mi = 0; mi < 4; ++mi)
                af[mi] = *(const bf16x8*)&As[(wm*64 + mi*16 + c16)*64 + kk*32 + 8*g];
#pragma unroll
            for (int ni = 0; ni < 4; ++ni)
                bfr[ni] = *(const bf16x8*)&Bs[(wn*64 + ni*16 + c16)*64 + kk*32 + 8*g];
#pragma unroll
            for (int mi = 0; mi < 4; ++mi)
#pragma unroll
                for (int ni = 0; ni < 4; ++ni)
                    acc[mi][ni] = __builtin_amdgcn_mfma_f32_16x16x32_bf16(
                        af[mi], bfr[ni], acc[mi][ni], 0, 0, 0);
        }
    }

#pragma unroll
    for (int ni = 0; ni < 4; ++ni) {
        const long c = bcol + wn*64 + ni*16 + c16;
        const float bv = bias[c];
#pragma unroll
        for (int mi = 0; mi < 4; ++mi) {
#pragma unroll
            for (int i = 0; i < 4; ++i) {
                const long r = brow + wm*64 + mi*16 + g*4 + i;
                float v = (acc[mi][ni][i] + bv) * scale;
                if constexpr (EPI == 2) {
                    ((float*)out)[r*N + c] = v;
                } else {
                    ((float*)out)[r*N + c] = v + aux[r*N + c];
                }
            }
        }
    }
}

// ---------------- 256x256 8-phase GEMM (m201 template, T2+T3+T4+T5) ----------------
template<int EPI>
__global__ __launch_bounds__(512, 2) void gemm256(
    const bf16_t* __restrict__ A, const bf16_t* __restrict__ Bm,
    const float* __restrict__ bias, void* __restrict__ out,
    void* __restrict__ out_k, void* __restrict__ out_v,
    int M, int N, int K)
{
    __shared__ alignas(16) char lds[131072];
    const int tid = threadIdx.x;
    const int l   = tid & 63;
    const int wid = tid >> 6;            // 0..7
    const int wm  = wid >> 2, wn = wid & 3;
    const int c16 = l & 15,   g  = l >> 4;
    const int xsw = (c16 & 7) << 4;

    int lin = blockIdx.y * gridDim.x + blockIdx.x;
    int nwg = gridDim.x * gridDim.y;
    int swz = (lin & 7) * (nwg >> 3) + (lin >> 3);
    const long brow = (long)(swz / gridDim.x) * 256;
    const long bcol = (long)(swz % gridDim.x) * 256;

    const int rowloc = tid >> 3;
    const int srcblk = (tid & 7) ^ ((tid >> 3) & 7);
    const bf16_t* Asrc = A  + (brow + rowloc) * (long)K + srcblk * 8;
    const bf16_t* Bsrc = Bm + (bcol + rowloc) * (long)K + srcblk * 8;

    f32x4 acc[8][4] = {};
    const int NKT = K >> 6;

    auto stA = [&](int cur, int t, int j) {
        gload16(Asrc + (long)j*64*K + (long)t*64, lds + cur*65536 + j*8192 + tid*16);
    };
    auto stB = [&](int cur, int t, int j) {
        gload16(Bsrc + (long)j*64*K + (long)t*64, lds + cur*65536 + 32768 + j*8192 + tid*16);
    };

#pragma unroll
    for (int j = 0; j < 4; ++j) stA(0, 0, j);
#pragma unroll
    for (int j = 0; j < 4; ++j) stB(0, 0, j);
#pragma unroll
    for (int j = 0; j < 4; ++j) stA(1, 1, j);
#pragma unroll
    for (int j = 0; j < 4; ++j) stB(1, 1, j);
    asm volatile("s_waitcnt vmcnt(8)" ::: "memory");
    __builtin_amdgcn_sched_barrier(0);
    __builtin_amdgcn_s_barrier();

    int cur = 0;
    for (int t = 0; t < NKT; ++t, cur ^= 1) {
        const char* aL = lds + cur*65536;
        const char* bL = aL + 32768;
        const bool stg = (t + 2 < NKT);
        bf16x8 a0[4][2], a1[4][2], b0[2][2], b1[2][2];

#pragma unroll
        for (int mi = 0; mi < 4; ++mi)
#pragma unroll
            for (int kk = 0; kk < 2; ++kk)
                a0[mi][kk] = *(const bf16x8*)(aL + (wm*128 + mi*16 + c16)*128 + ((kk*64 + 16*g) ^ xsw));
#pragma unroll
        for (int ni = 0; ni < 2; ++ni)
#pragma unroll
            for (int kk = 0; kk < 2; ++kk)
                b0[ni][kk] = *(const bf16x8*)(bL + (wn*64 + ni*16 + c16)*128 + ((kk*64 + 16*g) ^ xsw));
        __builtin_amdgcn_s_barrier();
        asm volatile("s_waitcnt lgkmcnt(0)" ::: "memory");
        __builtin_amdgcn_sched_barrier(0);
        __builtin_amdgcn_s_setprio(1);
#pragma unroll
        for (int mi = 0; mi < 4; ++mi)
#pragma unroll
            for (int ni = 0; ni < 2; ++ni)
#pragma unroll
                for (int kk = 0; kk < 2; ++kk)
                    acc[mi][ni] = __builtin_amdgcn_mfma_f32_16x16x32_bf16(a0[mi][kk], b0[ni][kk], acc[mi][ni], 0, 0, 0);
        __builtin_amdgcn_s_setprio(0);
        __builtin_amdgcn_s_barrier();

#pragma unroll
        for (int ni = 0; ni < 2; ++ni)
#pragma unroll
            for (int kk = 0; kk < 2; ++kk)
                b1[ni][kk] = *(const bf16x8*)(bL + (wn*64 + (ni+2)*16 + c16)*128 + ((kk*64 + 16*g) ^ xsw));
        if (stg) { stA(cur, t+2, 0); stA(cur, t+2, 2); }
        __builtin_amdgcn_s_barrier();
        asm volatile("s_waitcnt lgkmcnt(0)" ::: "memory");
        __builtin_amdgcn_sched_barrier(0);
        __builtin_amdgcn_s_setprio(1);
#pragma unroll
        for (int mi = 0; mi < 4; ++mi)
#pragma unroll
            for (int ni = 0; ni < 2; ++ni)
#pragma unroll
                for (int kk = 0; kk < 2; ++kk)
                    acc[mi][ni+2] = __builtin_amdgcn_mfma_f32_16x16x32_bf16(a0[mi][kk], b1[ni][kk], acc[mi][ni+2], 0, 0, 0);
        __builtin_amdgcn_s_setprio(0);
        __builtin_amdgcn_s_barrier();

#pragma unroll
        for (int mi = 0; mi < 4; ++mi)
#pragma unroll
            for (int kk = 0; kk < 2; ++kk)
                a1[mi][kk] = *(const bf16x8*)(aL + (wm*128 + (mi+4)*16 + c16)*128 + ((kk*64 + 16*g) ^ xsw));
        if (stg) { stB(cur, t+2, 0); stB(cur, t+2, 1); }
        __builtin_amdgcn_s_barrier();
        asm volatile("s_waitcnt lgkmcnt(0)" ::: "memory");
        __builtin_amdgcn_sched_barrier(0);
        __builtin_amdgcn_s_setprio(1);
#pragma unroll
        for (int mi = 0; mi < 4; ++mi)
#pragma unroll
            for (int ni = 0; ni < 2; ++ni)
#pragma unroll
                for (int kk = 0; kk < 2; ++kk)
                    acc[mi+4][ni] = __builtin_amdgcn_mfma_f32_16x16x32_bf16(a1[mi][kk], b0[ni][kk], acc[mi+4][ni], 0, 0, 0);
        __builtin_amdgcn_s_setprio(0);
        __builtin_amdgcn_s_barrier();

        if (stg) { stA(cur, t+2, 1); stA(cur, t+2, 3); stB(cur, t+2, 2); stB(cur, t+2, 3); }
        __builtin_amdgcn_s_barrier();
        __builtin_amdgcn_s_setprio(1);
#pragma unroll
        for (int mi = 0; mi < 4; ++mi)
#pragma unroll
            for (int ni = 0; ni < 2; ++ni)
#pragma unroll
                for (int kk = 0; kk < 2; ++kk)
                    acc[mi+4][ni+2] = __builtin_amdgcn_mfma_f32_16x16x32_bf16(a1[mi][kk], b1[ni][kk], acc[mi+4][ni+2], 0, 0, 0);
        __builtin_amdgcn_s_setprio(0);
        if (stg)                asm volatile("s_waitcnt vmcnt(8)" ::: "memory");
        else if (t < NKT - 1)   asm volatile("s_waitcnt vmcnt(0)" ::: "memory");
        __builtin_amdgcn_sched_barrier(0);
        __builtin_amdgcn_s_barrier();
    }

#pragma unroll
    for (int ni = 0; ni < 4; ++ni) {
        const long c = bcol + wn*64 + ni*16 + c16;
        const float bv = bias[c];
#pragma unroll
        for (int mi = 0; mi < 8; ++mi) {
#pragma unroll
            for (int i = 0; i < 4; ++i) {
                const long r = brow + wm*128 + mi*16 + g*4 + i;
                float v = acc[mi][ni][i] + bv;
                if constexpr (EPI == 3) {
                    ((bf16_t*)out)[r*N + c] = (bf16_t)fmaxf(v, 0.f);
                } else {   // EPI 5
                    const int mat = (int)(c >> 10);
                    const int hc  = (int)(c & 1023);
                    const long bb = r >> 11, sidx = r & (SEQ-1);
                    const long hb = bb*NHEAD + (hc >> 6);
                    if (mat == 0)
                        ((bf16_t*)out)[(hb*SEQ + sidx)*HDIM + (hc & 63)] = (bf16_t)(v * QSCALE);
                    else if (mat == 1)
                        ((bf16_t*)out_k)[(hb*SEQ + sidx)*HDIM + (hc & 63)] = (bf16_t)v;
                    else
                        ((bf16_t*)out_v)[(hb*HDIM + (hc & 63))*SEQ + sidx] = (bf16_t)v;
                }
            }
        }
    }
}

// ---------------- flash attention: 64 q-rows/wave, swapped-QK, exp2, shuffle-free softmax ----------
// grid 512, 4 waves/block, 64 q-rows per wave (4 x 16-row fragments). R9 postmortem: residency is
// register-capped at ~2 waves/SIMD, so this round doubles per-wave ILP instead: 64 MFMA per 64-key
// tile against the SAME per-tile fixed costs (one K issue, one V issue, one lgkm drain, one fence
// set). Single statically-named K buffer: qf0-3 QK consume kr at tile start; reload same buffer
// right after (WAR via register dependence), covered by sm+pwrite+PV of the current tile.
__device__ __forceinline__ void kload(bf16x8 (&dst)[4][2], const bf16_t* kb0,
                                      int ktt, int c16, int g) {
    const bf16_t* kbase = kb0 + (size_t)ktt*64*HDIM;
#pragma unroll
    for (int jk = 0; jk < 4; ++jk)
#pragma unroll
        for (int ks = 0; ks < 2; ++ks)
            dst[jk][ks] = *(const bf16x8*)(kbase + (size_t)(16*jk + c16)*HDIM + ks*32 + 8*g);
}

__device__ __forceinline__ void vload(bf16x8 (&vr)[4][2], const bf16_t* vt0,
                                      int ktt, int c16, int g) {
#pragma unroll
    for (int nf = 0; nf < 4; ++nf)
#pragma unroll
        for (int ks = 0; ks < 2; ++ks)
            vr[nf][ks] = *(const bf16x8*)(vt0 + (size_t)(16*nf + c16)*SEQ + ktt*64 + ks*32 + 8*g);
}

// one qf fragment: QK^T swapped -> s[jk][i] = S[key=16jk+4g+i][q = qf*16+c16]
__device__ __forceinline__ void qk1(f32x4 (&s)[4], const bf16x8 (&kr)[4][2],
                                    const bf16x8 (&aqf)[2]) {
    const f32x4 z = {0.f, 0.f, 0.f, 0.f};
    __builtin_amdgcn_s_setprio(1);
#pragma unroll
    for (int jk = 0; jk < 4; ++jk) {
        s[jk] = __builtin_amdgcn_mfma_f32_16x16x32_bf16(kr[jk][0], aqf[0], z, 0, 0, 0);
        s[jk] = __builtin_amdgcn_mfma_f32_16x16x32_bf16(kr[jk][1], aqf[1], s[jk], 0, 0, 0);
    }
    __builtin_amdgcn_s_setprio(0);
}

// online softmax for one qf (log2 domain); steady state = zero cross-lane shuffles
__device__ __forceinline__ void sm1(f32x4 (&s)[4], f32x4 (&accf)[4],
                                    float& m, float& ls, int g) {
    f32x4 t01, t23, t03;
#pragma unroll
    for (int i = 0; i < 4; ++i) {
        t01[i] = fmaxf(s[0][i], s[1][i]);
        t23[i] = fmaxf(s[2][i], s[3][i]);
    }
#pragma unroll
    for (int i = 0; i < 4; ++i) t03[i] = fmaxf(t01[i], t23[i]);
    float lmax = fmaxf(fmaxf(t03[0], t03[1]), fmaxf(t03[2], t03[3]));
    if (__any(lmax > m + THR_LOG2)) {
        float pm = lmax;
        pm = fmaxf(pm, __shfl_xor(pm, 16, 64));
        pm = fmaxf(pm, __shfl_xor(pm, 32, 64));
        float mn   = fmaxf(m, pm);
        float corr = __builtin_exp2f(m - mn);
        ls *= corr;
        m   = mn;
        float c0 = __shfl(corr, 4*g + 0, 64);
        float c1 = __shfl(corr, 4*g + 1, 64);
        float c2 = __shfl(corr, 4*g + 2, 64);
        float c3 = __shfl(corr, 4*g + 3, 64);
#pragma unroll
        for (int nf = 0; nf < 4; ++nf) {
            accf[nf][0] *= c0; accf[nf][1] *= c1;
            accf[nf][2] *= c2; accf[nf][3] *= c3;
        }
    }
#pragma unroll
    for (int jk = 0; jk < 4; ++jk)
#pragma unroll
        for (int i = 0; i < 4; ++i)
            s[jk][i] = __builtin_exp2f(s[jk][i] - m);
    f32x4 r01, r23, r;
#pragma unroll
    for (int i = 0; i < 4; ++i) {
        r01[i] = s[0][i] + s[1][i];
        r23[i] = s[2][i] + s[3][i];
    }
#pragma unroll
    for (int i = 0; i < 4; ++i) r[i] = r01[i] + r23[i];
    ls += (r[0] + r[1]) + (r[2] + r[3]);
}

__device__ __forceinline__ void pw1(const f32x4 (&s)[4], char* buf, int qf, int c16, int g) {
#pragma unroll
    for (int jk = 0; jk < 4; ++jk) {
        bf16x4 pk;
        pk[0]=(bf16_t)s[jk][0]; pk[1]=(bf16_t)s[jk][1];
        pk[2]=(bf16_t)s[jk][2]; pk[3]=(bf16_t)s[jk][3];
        *(bf16x4*)(buf + (qf*16 + c16)*128 + ((32*jk + 8*g) ^ ((c16 & 7) << 4))) = pk;
    }
}

__device__ __forceinline__ void pv1(f32x4 (&accf)[4], const bf16x8 (&vr)[4][2],
                                    const char* buf, int qf, int c16, int g) {
    __builtin_amdgcn_s_setprio(1);
#pragma unroll
    for (int ks = 0; ks < 2; ++ks) {
        bf16x8 pa = *(const bf16x8*)(buf + (qf*16 + c16)*128 + ((ks*64 + 16*g) ^ ((c16 & 7) << 4)));
#pragma unroll
        for (int nf = 0; nf < 4; ++nf)
            accf[nf] = __builtin_amdgcn_mfma_f32_16x16x32_bf16(pa, vr[nf][ks], accf[nf], 0, 0, 0);
    }
    __builtin_amdgcn_s_setprio(0);
}

__global__ __launch_bounds__(256, 2) void attn_k(
    const bf16_t* __restrict__ qb, const bf16_t* __restrict__ kb,
    const bf16_t* __restrict__ vt, bf16_t* __restrict__ ctx)
{
    // XCD decode: xcd = id&7, 8 bh per XCD; 512 blocks total (single pass at 2 blocks/CU)
    const int id  = blockIdx.x;          // 0..511
    const int idx = id >> 3;             // 0..63
    const int bh  = (id & 7) + 8 * (idx & 7);
    const int qt  = idx >> 3;            // 0..7
    const int w   = threadIdx.x >> 6;
    const int l   = threadIdx.x & 63;
    const int c16 = l & 15, g = l >> 4;
    const int q0  = qt*256 + w*64;

    __shared__ char Ps[4*16384];         // per-wave: 2 x 8KB P tiles (64 rows x 64 keys bf16)
    char* myP = &Ps[w*16384];

    bf16x8 aq[4][2];
#pragma unroll
    for (int qf = 0; qf < 4; ++qf) {
        const bf16_t* qrow = qb + ((size_t)bh*SEQ + q0 + qf*16 + c16)*HDIM;
        aq[qf][0] = *(const bf16x8*)(qrow + 8*g);
        aq[qf][1] = *(const bf16x8*)(qrow + 32 + 8*g);
    }

    const bf16_t* kb0 = kb + (size_t)bh*SEQ*HDIM;
    const bf16_t* vt0 = vt + (size_t)bh*HDIM*SEQ;

    f32x4 acc[4][4] = {};
    float m[4]  = {-1e30f, -1e30f, -1e30f, -1e30f};
    float ls[4] = {0.f, 0.f, 0.f, 0.f};

    bf16x8 kr[4][2], vr[4][2];
    f32x4 s[4];

    kload(kr, kb0, 0, c16, g);

    const int NT = SEQ/64;   // 32
    for (int t = 0; t < NT; ++t) {
        char* buf = myP + (t & 1) * 8192;
        // qf0..2: qk -> sm -> pwrite (s transient per qf)
        qk1(s, kr, aq[0]); sm1(s, acc[0], m[0], ls[0], g); pw1(s, buf, 0, c16, g);
        qk1(s, kr, aq[1]); sm1(s, acc[1], m[1], ls[1], g); pw1(s, buf, 1, c16, g);
        qk1(s, kr, aq[2]); sm1(s, acc[2], m[2], ls[2], g); pw1(s, buf, 2, c16, g);
        // qf3: after its QK, kr is dead -> refill same buffer for t+1; issue V(t)
        qk1(s, kr, aq[3]);
        if (t + 1 < NT) kload(kr, kb0, t + 1, c16, g);
        vload(vr, vt0, t, c16, g);
        __builtin_amdgcn_sched_barrier(0);               // pin load-issue point
        sm1(s, acc[3], m[3], ls[3], g); pw1(s, buf, 3, c16, g);
        // P visible wave-wide, then PV for all 4 qf
        asm volatile("s_waitcnt lgkmcnt(0)" ::: "memory");
        __builtin_amdgcn_sched_barrier(0);
        pv1(acc[0], vr, buf, 0, c16, g);
        pv1(acc[1], vr, buf, 1, c16, g);
        pv1(acc[2], vr, buf, 2, c16, g);
        pv1(acc[3], vr, buf, 3, c16, g);
        asm volatile("" ::: "memory");                   // pin P reads before next tile's writes
    }

    const int b = bh >> 4, h = bh & 15;
#pragma unroll
    for (int qf = 0; qf < 4; ++qf) {
        float lst = ls[qf];
        lst += __shfl_xor(lst, 16, 64);
        lst += __shfl_xor(lst, 32, 64);
        float i0 = 1.0f / __shfl(lst, 4*g + 0, 64);
        float i1 = 1.0f / __shfl(lst, 4*g + 1, 64);
        float i2 = 1.0f / __shfl(lst, 4*g + 2, 64);
        float i3 = 1.0f / __shfl(lst, 4*g + 3, 64);
#pragma unroll
        for (int nf = 0; nf < 4; ++nf) {
            long col = (size_t)h*HDIM + nf*16 + c16;
            long rb  = (size_t)b*SEQ + q0 + qf*16 + 4*g;
            ctx[(rb + 0)*DMODEL + col] = (bf16_t)(acc[qf][nf][0] * i0);
            ctx[(rb + 1)*DMODEL + col] = (bf16_t)(acc[qf][nf][1] * i1);
            ctx[(rb + 2)*DMODEL + col] = (bf16_t)(acc[qf][nf][2] * i2);
            ctx[(rb + 3)*DMODEL + col] = (bf16_t)(acc[qf][nf][3] * i3);
        }
    }
}

// ---------------- layer norm: one block per row of 1024 ----------------
__global__ __launch_bounds__(256) void ln_k(
    const float* __restrict__ a, const float* __restrict__ b,
    const float* __restrict__ g, const float* __restrict__ be,
    float* __restrict__ of, bf16_t* __restrict__ ob)
{
    const long row = blockIdx.x;
    const int tid = threadIdx.x;
    float4 v = ((const float4*)(a + row*DMODEL))[tid];
    if (b) {
        float4 u = ((const float4*)(b + row*DMODEL))[tid];
        v.x += u.x; v.y += u.y; v.z += u.z; v.w += u.w;
    }
    float s = v.x + v.y + v.z + v.w;
    float q = v.x*v.x + v.y*v.y + v.z*v.z + v.w*v.w;
#pragma unroll
    for (int msk = 1; msk < 64; msk <<= 1) {
        s += __shfl_xor(s, msk, 64);
        q += __shfl_xor(q, msk, 64);
    }
    __shared__ float sb[4], qb2[4];
    int w = tid >> 6, lid = tid & 63;
    if (lid == 0) { sb[w] = s; qb2[w] = q; }
    __syncthreads();
    s = sb[0] + sb[1] + sb[2] + sb[3];
    q = qb2[0] + qb2[1] + qb2[2] + qb2[3];
    float mean = s * (1.f/1024.f);
    float var  = q * (1.f/1024.f) - mean*mean;
    float rs   = rsqrtf(var + 1e-5f);
    float4 gv = ((const float4*)g)[tid];
    float4 bv = ((const float4*)be)[tid];
    float o0 = (v.x-mean)*rs*gv.x + bv.x;
    float o1 = (v.y-mean)*rs*gv.y + bv.y;
    float o2 = (v.z-mean)*rs*gv.z + bv.z;
    float o3 = (v.w-mean)*rs*gv.w + bv.w;
    if (ob) {
        bf16x4 o; o[0]=(bf16_t)o0; o[1]=(bf16_t)o1; o[2]=(bf16_t)o2; o[3]=(bf16_t)o3;
        *(bf16x4*)(ob + row*DMODEL + tid*4) = o;
    } else {
        float4 o = make_float4(o0, o1, o2, o3);
        ((float4*)(of + row*DMODEL))[tid] = o;
    }
}

// ---------------- host ----------------
extern "C" void kernel_launch(void* const* d_in, const int* in_sizes, int n_in,
                              void* d_out, int out_size, void* d_ws, size_t ws_size,
                              hipStream_t stream)
{
    const float* x   = (const float*)d_in[0];
    const float* Wq  = (const float*)d_in[1];
    const float* bq  = (const float*)d_in[2];
    const float* Wk  = (const float*)d_in[3];
    const float* bk  = (const float*)d_in[4];
    const float* Wv  = (const float*)d_in[5];
    const float* bvv = (const float*)d_in[6];
    const float* Wo  = (const float*)d_in[7];
    const float* bo  = (const float*)d_in[8];
    const float* W1  = (const float*)d_in[9];
    const float* b1  = (const float*)d_in[10];
    const float* W2  = (const float*)d_in[11];
    const float* b2  = (const float*)d_in[12];
    const float* g1  = (const float*)d_in[13];
    const float* be1 = (const float*)d_in[14];
    const float* g2  = (const float*)d_in[15];
    const float* be2 = (const float*)d_in[16];

    char* ws = (char*)d_ws;
    bf16_t* xb   = (bf16_t*)(ws + XB_OFF);
    bf16_t* qbuf = (bf16_t*)(ws + Q_OFF);
    bf16_t* kbuf = (bf16_t*)(ws + K_OFF);
    bf16_t* vtb  = (bf16_t*)(ws + VT_OFF);
    bf16_t* ffn1 = (bf16_t*)(ws + FFN1_OFF);
    bf16_t* ctxb = (bf16_t*)(ws + CTX_OFF);
    float*  out1 = (float*)(ws + OUT1_OFF);
    bf16_t* ln1b = (bf16_t*)(ws + LN1_OFF);
    bf16_t* wqkv = (bf16_t*)(ws + WQKV_OFF);
    bf16_t* wob  = (bf16_t*)(ws + WO_OFF);
    bf16_t* w1b  = (bf16_t*)(ws + W1_OFF);
    bf16_t* w2b  = (bf16_t*)(ws + W2_OFF);
    float*  biasc= (float*)(ws + OUT1_OFF);   // 3072 floats, dead before Wo writes out1
    float*  dout = (float*)d_out;

    auto cast = [&](const float* s, bf16_t* d, long n) {
        int n8 = (int)(n / 8);
        cast_bf16_k<<<(n8 + 255)/256, 256, 0, stream>>>(s, d, n8);
    };
    cast(x,  xb,  (long)MTOK*DMODEL);
    cast(Wq, wqkv,                        (long)DMODEL*DMODEL);
    cast(Wk, wqkv + (long)DMODEL*DMODEL,  (long)DMODEL*DMODEL);
    cast(Wv, wqkv + 2L*DMODEL*DMODEL,     (long)DMODEL*DMODEL);
    cast(Wo, wob, (long)DMODEL*DMODEL);
    cast(W1, w1b, (long)DFF*DMODEL);
    cast(W2, w2b, (long)DMODEL*DFF);
    concat_bias_k<<<12, 256, 0, stream>>>(bq, bk, bvv, biasc);

    // fused QKV projection: 256^2 8-phase (Q scaled by QSCALE = 0.125*log2e in epilogue)
    gemm256<5><<<dim3(3*DMODEL/256, MTOK/256), dim3(512), 0, stream>>>(
        xb, wqkv, biasc, qbuf, kbuf, vtb, MTOK, 3*DMODEL, DMODEL);
    // attention (512 blocks, 64 q-rows/wave)
    attn_k<<<dim3(512), dim3(256), 0, stream>>>(qbuf, kbuf, vtb, ctxb);
    // Wo projection -> out1 (fp32), 128^2
    gemm_bt<2><<<dim3(DMODEL/128, MTOK/128), dim3(256), 0, stream>>>(
        ctxb, wob, bo, out1, nullptr, MTOK, DMODEL, DMODEL, 1.f);
    // LN1
    ln_k<<<MTOK, dim3(256), 0, stream>>>(x, out1, g1, be1, nullptr, ln1b);
    // FFN1: relu(ln1 @ W1^T + b1) -> bf16, 256^2 8-phase
    gemm256<3><<<dim3(DFF/256, MTOK/256), dim3(512), 0, stream>>>(
        ln1b, w1b, b1, ffn1, nullptr, nullptr, MTOK, DFF, DMODEL);
    // FFN2: s2 = out1 + (ffn1 @ W2^T + b2) -> fp32 in place, 128^2
    gemm_bt<4><<<dim3(DMODEL/128, MTOK/128), dim3(256), 0, stream>>>(
        ffn1, w2b, b2, out1, out1, MTOK, DMODEL, DFF, 1.f);
    // LN2 -> d_out
    ln_k<<<MTOK, dim3(256), 0, stream>>>(out1, nullptr, g2, be2, dout, nullptr);
}

// Round 11
// 485.616 us; speedup vs baseline: 1.2392x; 1.1862x over previous
//
#include <hip/hip_runtime.h>

typedef __bf16 bf16_t;
typedef __bf16 bf16x8 __attribute__((ext_vector_type(8)));
typedef __bf16 bf16x4 __attribute__((ext_vector_type(4)));
typedef float  f32x4  __attribute__((ext_vector_type(4)));

#define SEQ   2048
#define DMODEL 1024
#define DFF   4096
#define NHEAD 16
#define HDIM  64
#define MTOK  8192   // 4 * 2048

// Q is pre-scaled by (1/sqrt(64)) * log2(e) so attention softmax runs in exp2 domain.
#define QSCALE 0.18033688f
#define THR_LOG2 11.5f

// ---------------- workspace layout (bytes) ----------------
#define MB (size_t)(1024*1024)
static const size_t XB_OFF   = 0;          // bf16 [8192][1024]  (aliased by FFN1 later)
static const size_t Q_OFF    = 16*MB;      // bf16 [B,H,S,64]
static const size_t K_OFF    = 32*MB;      // bf16 [B,H,S,64]
static const size_t VT_OFF   = 48*MB;      // bf16 [B,H,64,S]
static const size_t FFN1_OFF = 0;          // bf16 [8192][4096] aliases XB..VT (all dead then)
static const size_t CTX_OFF  = 64*MB;      // bf16 [8192][1024]
static const size_t OUT1_OFF = 80*MB;      // f32  [8192][1024]; bias-concat scratch earlier
static const size_t LN1_OFF  = 112*MB;     // bf16 [8192][1024]
static const size_t WQKV_OFF = 128*MB;     // bf16 [3072][1024] (Q,K,V rows concat)
static const size_t WO_OFF   = 134*MB;
static const size_t W1_OFF   = 136*MB;     // bf16 [4096][1024]
static const size_t W2_OFF   = 144*MB;     // bf16 [1024][4096]  (ends at 152MB)

// ---------------- helpers ----------------
__device__ inline void gload16(const void* g, void* l) {
    __builtin_amdgcn_global_load_lds((__attribute__((address_space(1))) void*)g,
                                     (__attribute__((address_space(3))) void*)l, 16, 0, 0);
}

// ---------------- merged bf16 cast: all 7 tensors in one launch ----------------
// chunk boundaries (units of 8 elements):
// x 1048576 | Wq 131072 | Wk 131072 | Wv 131072 | Wo 131072 | W1 524288 | W2 524288
__global__ __launch_bounds__(256) void cast_all_k(
    const float* __restrict__ x,  const float* __restrict__ Wq,
    const float* __restrict__ Wk, const float* __restrict__ Wv,
    const float* __restrict__ Wo, const float* __restrict__ W1,
    const float* __restrict__ W2,
    bf16_t* __restrict__ xb, bf16_t* __restrict__ wqkv,
    bf16_t* __restrict__ wob, bf16_t* __restrict__ w1b, bf16_t* __restrict__ w2b)
{
    long i = (long)blockIdx.x * 256 + threadIdx.x;   // grid = 10240 * 256 = 2621440 exact
    const float* src; bf16_t* dst; long j;
    if      (i < 1048576) { src = x;  dst = xb;             j = i; }
    else if (i < 1179648) { src = Wq; dst = wqkv;           j = i - 1048576; }
    else if (i < 1310720) { src = Wk; dst = wqkv + 1048576; j = i - 1179648; }
    else if (i < 1441792) { src = Wv; dst = wqkv + 2097152; j = i - 1310720; }
    else if (i < 1572864) { src = Wo; dst = wob;            j = i - 1441792; }
    else if (i < 2097152) { src = W1; dst = w1b;            j = i - 1572864; }
    else                  { src = W2; dst = w2b;            j = i - 2097152; }
    float4 v0 = ((const float4*)src)[2*j];
    float4 v1 = ((const float4*)src)[2*j+1];
    bf16x8 o;
    o[0]=(bf16_t)v0.x; o[1]=(bf16_t)v0.y; o[2]=(bf16_t)v0.z; o[3]=(bf16_t)v0.w;
    o[4]=(bf16_t)v1.x; o[5]=(bf16_t)v1.y; o[6]=(bf16_t)v1.z; o[7]=(bf16_t)v1.w;
    *(bf16x8*)(dst + j*8) = o;
}

__global__ __launch_bounds__(256) void concat_bias_k(const float* __restrict__ a,
                                                     const float* __restrict__ b,
                                                     const float* __restrict__ c,
                                                     float* __restrict__ o) {
    int i = blockIdx.x * 256 + threadIdx.x;   // grid 12*256 = 3072
    o[i] = (i < 1024) ? a[i] : ((i < 2048) ? b[i - 1024] : c[i - 2048]);
}

// ---------------- 128x128 GEMM (m97-class): used for Wo (EPI2) and FFN2 (EPI4) ----------------
template<int EPI>
__global__ __launch_bounds__(256, 2) void gemm_bt(
    const bf16_t* __restrict__ A, const bf16_t* __restrict__ Bm,
    const float* __restrict__ bias, void* __restrict__ out,
    const float* __restrict__ aux, int M, int N, int K, float scale)
{
    __shared__ bf16_t As[128*64];
    __shared__ bf16_t Bs[128*64];
    const int tid = threadIdx.x;
    const int l   = tid & 63;
    const int wid = tid >> 6;
    const int wm  = wid >> 1, wn = wid & 1;
    const int c16 = l & 15,   g  = l >> 4;
    int lin = blockIdx.y * gridDim.x + blockIdx.x;
    int nwg = gridDim.x * gridDim.y;
    int swz = (lin & 7) * (nwg >> 3) + (lin >> 3);
    const long brow = (long)(swz / gridDim.x) * 128;
    const long bcol = (long)(swz % gridDim.x) * 128;

    f32x4 acc[4][4] = {};

    const int nkt = K >> 6;
    for (int kt = 0; kt < nkt; ++kt) {
        __syncthreads();
        const bf16_t* Ag = A  + brow * K + kt*64;
        const bf16_t* Bg = Bm + bcol * K + kt*64;
#pragma unroll
        for (int c = 0; c < 4; ++c) {
            int e   = (c*256 + tid) * 8;
            int row = e >> 6;
            int col = e & 63;
            gload16(Ag + (long)row*K + col, &As[e]);
            gload16(Bg + (long)row*K + col, &Bs[e]);
        }
        __syncthreads();
#pragma unroll
        for (int kk = 0; kk < 2; ++kk) {
            bf16x8 af[4], bfr[4];
#pragma unroll
            for (int mi = 0; mi < 4; ++mi)
                af[mi] = *(const bf16x8*)&As[(wm*64 + mi*16 + c16)*64 + kk*32 + 8*g];
#pragma unroll
            for (int ni = 0; ni < 4; ++ni)
                bfr[ni] = *(const bf16x8*)&Bs[(wn*64 + ni*16 + c16)*64 + kk*32 + 8*g];
#pragma unroll
            for (int mi = 0; mi < 4; ++mi)
#pragma unroll
                for (int ni = 0; ni < 4; ++ni)
                    acc[mi][ni] = __builtin_amdgcn_mfma_f32_16x16x32_bf16(
                        af[mi], bfr[ni], acc[mi][ni], 0, 0, 0);
        }
    }

#pragma unroll
    for (int ni = 0; ni < 4; ++ni) {
        const long c = bcol + wn*64 + ni*16 + c16;
        const float bv = bias[c];
#pragma unroll
        for (int mi = 0; mi < 4; ++mi) {
#pragma unroll
            for (int i = 0; i < 4; ++i) {
                const long r = brow + wm*64 + mi*16 + g*4 + i;
                float v = (acc[mi][ni][i] + bv) * scale;
                if constexpr (EPI == 2) {
                    ((float*)out)[r*N + c] = v;
                } else {
                    ((float*)out)[r*N + c] = v + aux[r*N + c];
                }
            }
        }
    }
}

// ---------------- 256x256 8-phase GEMM (m201 template, T2+T3+T4+T5) ----------------
template<int EPI>
__global__ __launch_bounds__(512, 2) void gemm256(
    const bf16_t* __restrict__ A, const bf16_t* __restrict__ Bm,
    const float* __restrict__ bias, void* __restrict__ out,
    void* __restrict__ out_k, void* __restrict__ out_v,
    int M, int N, int K)
{
    __shared__ alignas(16) char lds[131072];
    const int tid = threadIdx.x;
    const int l   = tid & 63;
    const int wid = tid >> 6;            // 0..7
    const int wm  = wid >> 2, wn = wid & 3;
    const int c16 = l & 15,   g  = l >> 4;
    const int xsw = (c16 & 7) << 4;

    int lin = blockIdx.y * gridDim.x + blockIdx.x;
    int nwg = gridDim.x * gridDim.y;
    int swz = (lin & 7) * (nwg >> 3) + (lin >> 3);
    const long brow = (long)(swz / gridDim.x) * 256;
    const long bcol = (long)(swz % gridDim.x) * 256;

    const int rowloc = tid >> 3;
    const int srcblk = (tid & 7) ^ ((tid >> 3) & 7);
    const bf16_t* Asrc = A  + (brow + rowloc) * (long)K + srcblk * 8;
    const bf16_t* Bsrc = Bm + (bcol + rowloc) * (long)K + srcblk * 8;

    f32x4 acc[8][4] = {};
    const int NKT = K >> 6;

    auto stA = [&](int cur, int t, int j) {
        gload16(Asrc + (long)j*64*K + (long)t*64, lds + cur*65536 + j*8192 + tid*16);
    };
    auto stB = [&](int cur, int t, int j) {
        gload16(Bsrc + (long)j*64*K + (long)t*64, lds + cur*65536 + 32768 + j*8192 + tid*16);
    };

#pragma unroll
    for (int j = 0; j < 4; ++j) stA(0, 0, j);
#pragma unroll
    for (int j = 0; j < 4; ++j) stB(0, 0, j);
#pragma unroll
    for (int j = 0; j < 4; ++j) stA(1, 1, j);
#pragma unroll
    for (int j = 0; j < 4; ++j) stB(1, 1, j);
    asm volatile("s_waitcnt vmcnt(8)" ::: "memory");
    __builtin_amdgcn_sched_barrier(0);
    __builtin_amdgcn_s_barrier();

    int cur = 0;
    for (int t = 0; t < NKT; ++t, cur ^= 1) {
        const char* aL = lds + cur*65536;
        const char* bL = aL + 32768;
        const bool stg = (t + 2 < NKT);
        bf16x8 a0[4][2], a1[4][2], b0[2][2], b1[2][2];

#pragma unroll
        for (int mi = 0; mi < 4; ++mi)
#pragma unroll
            for (int kk = 0; kk < 2; ++kk)
                a0[mi][kk] = *(const bf16x8*)(aL + (wm*128 + mi*16 + c16)*128 + ((kk*64 + 16*g) ^ xsw));
#pragma unroll
        for (int ni = 0; ni < 2; ++ni)
#pragma unroll
            for (int kk = 0; kk < 2; ++kk)
                b0[ni][kk] = *(const bf16x8*)(bL + (wn*64 + ni*16 + c16)*128 + ((kk*64 + 16*g) ^ xsw));
        __builtin_amdgcn_s_barrier();
        asm volatile("s_waitcnt lgkmcnt(0)" ::: "memory");
        __builtin_amdgcn_sched_barrier(0);
        __builtin_amdgcn_s_setprio(1);
#pragma unroll
        for (int mi = 0; mi < 4; ++mi)
#pragma unroll
            for (int ni = 0; ni < 2; ++ni)
#pragma unroll
                for (int kk = 0; kk < 2; ++kk)
                    acc[mi][ni] = __builtin_amdgcn_mfma_f32_16x16x32_bf16(a0[mi][kk], b0[ni][kk], acc[mi][ni], 0, 0, 0);
        __builtin_amdgcn_s_setprio(0);
        __builtin_amdgcn_s_barrier();

#pragma unroll
        for (int ni = 0; ni < 2; ++ni)
#pragma unroll
            for (int kk = 0; kk < 2; ++kk)
                b1[ni][kk] = *(const bf16x8*)(bL + (wn*64 + (ni+2)*16 + c16)*128 + ((kk*64 + 16*g) ^ xsw));
        if (stg) { stA(cur, t+2, 0); stA(cur, t+2, 2); }
        __builtin_amdgcn_s_barrier();
        asm volatile("s_waitcnt lgkmcnt(0)" ::: "memory");
        __builtin_amdgcn_sched_barrier(0);
        __builtin_amdgcn_s_setprio(1);
#pragma unroll
        for (int mi = 0; mi < 4; ++mi)
#pragma unroll
            for (int ni = 0; ni < 2; ++ni)
#pragma unroll
                for (int kk = 0; kk < 2; ++kk)
                    acc[mi][ni+2] = __builtin_amdgcn_mfma_f32_16x16x32_bf16(a0[mi][kk], b1[ni][kk], acc[mi][ni+2], 0, 0, 0);
        __builtin_amdgcn_s_setprio(0);
        __builtin_amdgcn_s_barrier();

#pragma unroll
        for (int mi = 0; mi < 4; ++mi)
#pragma unroll
            for (int kk = 0; kk < 2; ++kk)
                a1[mi][kk] = *(const bf16x8*)(aL + (wm*128 + (mi+4)*16 + c16)*128 + ((kk*64 + 16*g) ^ xsw));
        if (stg) { stB(cur, t+2, 0); stB(cur, t+2, 1); }
        __builtin_amdgcn_s_barrier();
        asm volatile("s_waitcnt lgkmcnt(0)" ::: "memory");
        __builtin_amdgcn_sched_barrier(0);
        __builtin_amdgcn_s_setprio(1);
#pragma unroll
        for (int mi = 0; mi < 4; ++mi)
#pragma unroll
            for (int ni = 0; ni < 2; ++ni)
#pragma unroll
                for (int kk = 0; kk < 2; ++kk)
                    acc[mi+4][ni] = __builtin_amdgcn_mfma_f32_16x16x32_bf16(a1[mi][kk], b0[ni][kk], acc[mi+4][ni], 0, 0, 0);
        __builtin_amdgcn_s_setprio(0);
        __builtin_amdgcn_s_barrier();

        if (stg) { stA(cur, t+2, 1); stA(cur, t+2, 3); stB(cur, t+2, 2); stB(cur, t+2, 3); }
        __builtin_amdgcn_s_barrier();
        __builtin_amdgcn_s_setprio(1);
#pragma unroll
        for (int mi = 0; mi < 4; ++mi)
#pragma unroll
            for (int ni = 0; ni < 2; ++ni)
#pragma unroll
                for (int kk = 0; kk < 2; ++kk)
                    acc[mi+4][ni+2] = __builtin_amdgcn_mfma_f32_16x16x32_bf16(a1[mi][kk], b1[ni][kk], acc[mi+4][ni+2], 0, 0, 0);
        __builtin_amdgcn_s_setprio(0);
        if (stg)                asm volatile("s_waitcnt vmcnt(8)" ::: "memory");
        else if (t < NKT - 1)   asm volatile("s_waitcnt vmcnt(0)" ::: "memory");
        __builtin_amdgcn_sched_barrier(0);
        __builtin_amdgcn_s_barrier();
    }

#pragma unroll
    for (int ni = 0; ni < 4; ++ni) {
        const long c = bcol + wn*64 + ni*16 + c16;
        const float bv = bias[c];
#pragma unroll
        for (int mi = 0; mi < 8; ++mi) {
#pragma unroll
            for (int i = 0; i < 4; ++i) {
                const long r = brow + wm*128 + mi*16 + g*4 + i;
                float v = acc[mi][ni][i] + bv;
                if constexpr (EPI == 3) {
                    ((bf16_t*)out)[r*N + c] = (bf16_t)fmaxf(v, 0.f);
                } else {   // EPI 5
                    const int mat = (int)(c >> 10);
                    const int hc  = (int)(c & 1023);
                    const long bb = r >> 11, sidx = r & (SEQ-1);
                    const long hb = bb*NHEAD + (hc >> 6);
                    if (mat == 0)
                        ((bf16_t*)out)[(hb*SEQ + sidx)*HDIM + (hc & 63)] = (bf16_t)(v * QSCALE);
                    else if (mat == 1)
                        ((bf16_t*)out_k)[(hb*SEQ + sidx)*HDIM + (hc & 63)] = (bf16_t)v;
                    else
                        ((bf16_t*)out_v)[(hb*HDIM + (hc & 63))*SEQ + sidx] = (bf16_t)v;
                }
            }
        }
    }
}

// ---------------- flash attention: block-shared LDS K/V, swapped-QK, exp2 softmax ----------------
// grid 1024, 4 waves/block, 32 q-rows/wave (128 q-rows/block). K+V tiles staged ONCE per block
// via global_load_lds (double-buffered 32KB, XOR-swizzled both-sides like gemm256); each wave
// reads fragments via ds_read_b128 (16-rows-same-col pattern -> T2 swizzle = conflict-free).
// P per-wave 4KB single-buffered (same-wave LDS ops are in-order; __syncthreads drains lgkm).
// LDS total 48KB -> 3 blocks/CU = 12 waves/CU (vs R10's 8). One barrier per tile; its implicit
// vmcnt(0) drains staging loads issued a full tile earlier.
__device__ __forceinline__ void qk1(f32x4 (&s)[4], const bf16x8 (&kr)[4][2],
                                    const bf16x8 (&aqf)[2]) {
    const f32x4 z = {0.f, 0.f, 0.f, 0.f};
    __builtin_amdgcn_s_setprio(1);
#pragma unroll
    for (int jk = 0; jk < 4; ++jk) {
        s[jk] = __builtin_amdgcn_mfma_f32_16x16x32_bf16(kr[jk][0], aqf[0], z, 0, 0, 0);
        s[jk] = __builtin_amdgcn_mfma_f32_16x16x32_bf16(kr[jk][1], aqf[1], s[jk], 0, 0, 0);
    }
    __builtin_amdgcn_s_setprio(0);
}

__device__ __forceinline__ void sm1(f32x4 (&s)[4], f32x4 (&accf)[4],
                                    float& m, float& ls, int g) {
    f32x4 t01, t23, t03;
#pragma unroll
    for (int i = 0; i < 4; ++i) {
        t01[i] = fmaxf(s[0][i], s[1][i]);
        t23[i] = fmaxf(s[2][i], s[3][i]);
    }
#pragma unroll
    for (int i = 0; i < 4; ++i) t03[i] = fmaxf(t01[i], t23[i]);
    float lmax = fmaxf(fmaxf(t03[0], t03[1]), fmaxf(t03[2], t03[3]));
    if (__any(lmax > m + THR_LOG2)) {
        float pm = lmax;
        pm = fmaxf(pm, __shfl_xor(pm, 16, 64));
        pm = fmaxf(pm, __shfl_xor(pm, 32, 64));
        float mn   = fmaxf(m, pm);
        float corr = __builtin_exp2f(m - mn);
        ls *= corr;
        m   = mn;
        float c0 = __shfl(corr, 4*g + 0, 64);
        float c1 = __shfl(corr, 4*g + 1, 64);
        float c2 = __shfl(corr, 4*g + 2, 64);
        float c3 = __shfl(corr, 4*g + 3, 64);
#pragma unroll
        for (int nf = 0; nf < 4; ++nf) {
            accf[nf][0] *= c0; accf[nf][1] *= c1;
            accf[nf][2] *= c2; accf[nf][3] *= c3;
        }
    }
#pragma unroll
    for (int jk = 0; jk < 4; ++jk)
#pragma unroll
        for (int i = 0; i < 4; ++i)
            s[jk][i] = __builtin_exp2f(s[jk][i] - m);
    f32x4 r01, r23, r;
#pragma unroll
    for (int i = 0; i < 4; ++i) {
        r01[i] = s[0][i] + s[1][i];
        r23[i] = s[2][i] + s[3][i];
    }
#pragma unroll
    for (int i = 0; i < 4; ++i) r[i] = r01[i] + r23[i];
    ls += (r[0] + r[1]) + (r[2] + r[3]);
}

__device__ __forceinline__ void pw1(const f32x4 (&s)[4], char* buf, int qf, int c16, int g) {
#pragma unroll
    for (int jk = 0; jk < 4; ++jk) {
        bf16x4 pk;
        pk[0]=(bf16_t)s[jk][0]; pk[1]=(bf16_t)s[jk][1];
        pk[2]=(bf16_t)s[jk][2]; pk[3]=(bf16_t)s[jk][3];
        *(bf16x4*)(buf + (qf*16 + c16)*128 + ((32*jk + 8*g) ^ ((c16 & 7) << 4))) = pk;
    }
}

__device__ __forceinline__ void pv1(f32x4 (&accf)[4], const bf16x8 (&vr)[4][2],
                                    const char* buf, int qf, int c16, int g) {
    __builtin_amdgcn_s_setprio(1);
#pragma unroll
    for (int ks = 0; ks < 2; ++ks) {
        bf16x8 pa = *(const bf16x8*)(buf + (qf*16 + c16)*128 + ((ks*64 + 16*g) ^ ((c16 & 7) << 4)));
#pragma unroll
        for (int nf = 0; nf < 4; ++nf)
            accf[nf] = __builtin_amdgcn_mfma_f32_16x16x32_bf16(pa, vr[nf][ks], accf[nf], 0, 0, 0);
    }
    __builtin_amdgcn_s_setprio(0);
}

__global__ __launch_bounds__(256, 3) void attn_k(
    const bf16_t* __restrict__ qb, const bf16_t* __restrict__ kb,
    const bf16_t* __restrict__ vt, bf16_t* __restrict__ ctx)
{
    // XCD decode: xcd = id&7, 8 bh per XCD (K/V 4MB = one XCD's L2)
    const int id  = blockIdx.x;           // 0..1023
    const int idx = id >> 3;              // 0..127
    const int bh  = (id & 7) + 8 * (idx & 7);
    const int qt  = idx >> 3;             // 0..15
    const int tid = threadIdx.x;
    const int w   = tid >> 6;
    const int l   = tid & 63;
    const int c16 = l & 15, g = l >> 4;
    const int q0  = qt*128 + w*32;
    const int xsw = (c16 & 7) << 4;

    __shared__ alignas(16) char kvLds[2][16384];   // [buf][K 8KB | V 8KB]
    __shared__ alignas(16) char Ps[4][4096];       // per-wave P (single-buffered)
    char* myP = Ps[w];

    bf16x8 aq[2][2];
#pragma unroll
    for (int qf = 0; qf < 2; ++qf) {
        const bf16_t* qrow = qb + ((size_t)bh*SEQ + q0 + qf*16 + c16)*HDIM;
        aq[qf][0] = *(const bf16x8*)(qrow + 8*g);
        aq[qf][1] = *(const bf16x8*)(qrow + 32 + 8*g);
    }

    const bf16_t* kb0 = kb + (size_t)bh*SEQ*HDIM;
    const bf16_t* vt0 = vt + (size_t)bh*HDIM*SEQ;

    // staging: slot s = j*256+tid (j=0,1), row = s>>3, 16B-block = (s&7)^(row&7) pre-swizzled
    const int r0 = tid >> 3;
    const int r1 = (256 + tid) >> 3;
    const int b0 = (tid & 7) ^ (r0 & 7);
    const int b1 = (tid & 7) ^ (r1 & 7);
    const bf16_t* ksrc0 = kb0 + (size_t)r0*HDIM + b0*8;
    const bf16_t* ksrc1 = kb0 + (size_t)r1*HDIM + b1*8;
    const bf16_t* vsrc0 = vt0 + (size_t)r0*SEQ + b0*8;
    const bf16_t* vsrc1 = vt0 + (size_t)r1*SEQ + b1*8;

    auto stage = [&](int buf, int t) {
        char* kd = kvLds[buf];
        char* vd = kd + 8192;
        gload16(ksrc0 + (size_t)t*64*HDIM, kd + tid*16);
        gload16(ksrc1 + (size_t)t*64*HDIM, kd + 4096 + tid*16);
        gload16(vsrc0 + t*64, vd + tid*16);
        gload16(vsrc1 + t*64, vd + 4096 + tid*16);
    };

    f32x4 acc[2][4] = {};
    float m[2]  = {-1e30f, -1e30f};
    float ls[2] = {0.f, 0.f};
    f32x4 s[4];

    stage(0, 0);
    __syncthreads();                       // implicit vmcnt(0): buf0 ready

    const int NT = SEQ/64;   // 32
    for (int t = 0; t < NT; ++t) {
        const char* kd = kvLds[t & 1];
        const char* vd = kd + 8192;
        if (t + 1 < NT) stage((t + 1) & 1, t + 1);
        // fragment reads from LDS (conflict-free via both-sides swizzle)
        bf16x8 kr[4][2], vr[4][2];
#pragma unroll
        for (int jk = 0; jk < 4; ++jk)
#pragma unroll
            for (int ks = 0; ks < 2; ++ks)
                kr[jk][ks] = *(const bf16x8*)(kd + (16*jk + c16)*128 + ((ks*64 + 16*g) ^ xsw));
#pragma unroll
        for (int nf = 0; nf < 4; ++nf)
#pragma unroll
            for (int ks = 0; ks < 2; ++ks)
                vr[nf][ks] = *(const bf16x8*)(vd + (16*nf + c16)*128 + ((ks*64 + 16*g) ^ xsw));
        // per-qf: QK -> online softmax -> P write (s transient)
        qk1(s, kr, aq[0]); sm1(s, acc[0], m[0], ls[0], g); pw1(s, myP, 0, c16, g);
        qk1(s, kr, aq[1]); sm1(s, acc[1], m[1], ls[1], g); pw1(s, myP, 1, c16, g);
        asm volatile("s_waitcnt lgkmcnt(0)" ::: "memory");   // P visible wave-wide
        __builtin_amdgcn_sched_barrier(0);
        pv1(acc[0], vr, myP, 0, c16, g);
        pv1(acc[1], vr, myP, 1, c16, g);
        __syncthreads();                   // drains vmcnt(0): next KV buf staged; lgkm: all reads done
    }

    const int b = bh >> 4, h = bh & 15;
#pragma unroll
    for (int qf = 0; qf < 2; ++qf) {
        float lst = ls[qf];
        lst += __shfl_xor(lst, 16, 64);
        lst += __shfl_xor(lst, 32, 64);
        float i0 = 1.0f / __shfl(lst, 4*g + 0, 64);
        float i1 = 1.0f / __shfl(lst, 4*g + 1, 64);
        float i2 = 1.0f / __shfl(lst, 4*g + 2, 64);
        float i3 = 1.0f / __shfl(lst, 4*g + 3, 64);
#pragma unroll
        for (int nf = 0; nf < 4; ++nf) {
            long col = (size_t)h*HDIM + nf*16 + c16;
            long rb  = (size_t)b*SEQ + q0 + qf*16 + 4*g;
            ctx[(rb + 0)*DMODEL + col] = (bf16_t)(acc[qf][nf][0] * i0);
            ctx[(rb + 1)*DMODEL + col] = (bf16_t)(acc[qf][nf][1] * i1);
            ctx[(rb + 2)*DMODEL + col] = (bf16_t)(acc[qf][nf][2] * i2);
            ctx[(rb + 3)*DMODEL + col] = (bf16_t)(acc[qf][nf][3] * i3);
        }
    }
}

// ---------------- layer norm: one block per row of 1024 ----------------
__global__ __launch_bounds__(256) void ln_k(
    const float* __restrict__ a, const float* __restrict__ b,
    const float* __restrict__ g, const float* __restrict__ be,
    float* __restrict__ of, bf16_t* __restrict__ ob)
{
    const long row = blockIdx.x;
    const int tid = threadIdx.x;
    float4 v = ((const float4*)(a + row*DMODEL))[tid];
    if (b) {
        float4 u = ((const float4*)(b + row*DMODEL))[tid];
        v.x += u.x; v.y += u.y; v.z += u.z; v.w += u.w;
    }
    float s = v.x + v.y + v.z + v.w;
    float q = v.x*v.x + v.y*v.y + v.z*v.z + v.w*v.w;
#pragma unroll
    for (int msk = 1; msk < 64; msk <<= 1) {
        s += __shfl_xor(s, msk, 64);
        q += __shfl_xor(q, msk, 64);
    }
    __shared__ float sb[4], qb2[4];
    int w = tid >> 6, lid = tid & 63;
    if (lid == 0) { sb[w] = s; qb2[w] = q; }
    __syncthreads();
    s = sb[0] + sb[1] + sb[2] + sb[3];
    q = qb2[0] + qb2[1] + qb2[2] + qb2[3];
    float mean = s * (1.f/1024.f);
    float var  = q * (1.f/1024.f) - mean*mean;
    float rs   = rsqrtf(var + 1e-5f);
    float4 gv = ((const float4*)g)[tid];
    float4 bv = ((const float4*)be)[tid];
    float o0 = (v.x-mean)*rs*gv.x + bv.x;
    float o1 = (v.y-mean)*rs*gv.y + bv.y;
    float o2 = (v.z-mean)*rs*gv.z + bv.z;
    float o3 = (v.w-mean)*rs*gv.w + bv.w;
    if (ob) {
        bf16x4 o; o[0]=(bf16_t)o0; o[1]=(bf16_t)o1; o[2]=(bf16_t)o2; o[3]=(bf16_t)o3;
        *(bf16x4*)(ob + row*DMODEL + tid*4) = o;
    } else {
        float4 o = make_float4(o0, o1, o2, o3);
        ((float4*)(of + row*DMODEL))[tid] = o;
    }
}

// ---------------- host ----------------
extern "C" void kernel_launch(void* const* d_in, const int* in_sizes, int n_in,
                              void* d_out, int out_size, void* d_ws, size_t ws_size,
                              hipStream_t stream)
{
    const float* x   = (const float*)d_in[0];
    const float* Wq  = (const float*)d_in[1];
    const float* bq  = (const float*)d_in[2];
    const float* Wk  = (const float*)d_in[3];
    const float* bk  = (const float*)d_in[4];
    const float* Wv  = (const float*)d_in[5];
    const float* bvv = (const float*)d_in[6];
    const float* Wo  = (const float*)d_in[7];
    const float* bo  = (const float*)d_in[8];
    const float* W1  = (const float*)d_in[9];
    const float* b1  = (const float*)d_in[10];
    const float* W2  = (const float*)d_in[11];
    const float* b2  = (const float*)d_in[12];
    const float* g1  = (const float*)d_in[13];
    const float* be1 = (const float*)d_in[14];
    const float* g2  = (const float*)d_in[15];
    const float* be2 = (const float*)d_in[16];

    char* ws = (char*)d_ws;
    bf16_t* xb   = (bf16_t*)(ws + XB_OFF);
    bf16_t* qbuf = (bf16_t*)(ws + Q_OFF);
    bf16_t* kbuf = (bf16_t*)(ws + K_OFF);
    bf16_t* vtb  = (bf16_t*)(ws + VT_OFF);
    bf16_t* ffn1 = (bf16_t*)(ws + FFN1_OFF);
    bf16_t* ctxb = (bf16_t*)(ws + CTX_OFF);
    float*  out1 = (float*)(ws + OUT1_OFF);
    bf16_t* ln1b = (bf16_t*)(ws + LN1_OFF);
    bf16_t* wqkv = (bf16_t*)(ws + WQKV_OFF);
    bf16_t* wob  = (bf16_t*)(ws + WO_OFF);
    bf16_t* w1b  = (bf16_t*)(ws + W1_OFF);
    bf16_t* w2b  = (bf16_t*)(ws + W2_OFF);
    float*  biasc= (float*)(ws + OUT1_OFF);   // 3072 floats, dead before Wo writes out1
    float*  dout = (float*)d_out;

    // all bf16 casts in ONE launch (2621440 chunks of 8 elements)
    cast_all_k<<<10240, 256, 0, stream>>>(x, Wq, Wk, Wv, Wo, W1, W2,
                                          xb, wqkv, wob, w1b, w2b);
    concat_bias_k<<<12, 256, 0, stream>>>(bq, bk, bvv, biasc);

    // fused QKV projection: 256^2 8-phase (Q scaled by QSCALE = 0.125*log2e in epilogue)
    gemm256<5><<<dim3(3*DMODEL/256, MTOK/256), dim3(512), 0, stream>>>(
        xb, wqkv, biasc, qbuf, kbuf, vtb, MTOK, 3*DMODEL, DMODEL);
    // attention (1024 blocks, block-shared LDS K/V, 12 waves/CU target)
    attn_k<<<dim3(1024), dim3(256), 0, stream>>>(qbuf, kbuf, vtb, ctxb);
    // Wo projection -> out1 (fp32), 128^2
    gemm_bt<2><<<dim3(DMODEL/128, MTOK/128), dim3(256), 0, stream>>>(
        ctxb, wob, bo, out1, nullptr, MTOK, DMODEL, DMODEL, 1.f);
    // LN1
    ln_k<<<MTOK, dim3(256), 0, stream>>>(x, out1, g1, be1, nullptr, ln1b);
    // FFN1: relu(ln1 @ W1^T + b1) -> bf16, 256^2 8-phase
    gemm256<3><<<dim3(DFF/256, MTOK/256), dim3(512), 0, stream>>>(
        ln1b, w1b, b1, ffn1, nullptr, nullptr, MTOK, DFF, DMODEL);
    // FFN2: s2 = out1 + (ffn1 @ W2^T + b2) -> fp32 in place, 128^2
    gemm_bt<4><<<dim3(DMODEL/128, MTOK/128), dim3(256), 0, stream>>>(
        ffn1, w2b, b2, out1, out1, MTOK, DMODEL, DFF, 1.f);
    // LN2 -> d_out
    ln_k<<<MTOK, dim3(256), 0, stream>>>(out1, nullptr, g2, be2, dout, nullptr);
}